// Round 1
// 991.934 us; speedup vs baseline: 1.1406x; 1.1406x over previous
//
#include <hip/hip_runtime.h>
#include <hip/hip_fp16.h>

// CRF mean-field, NHWC. Per iter: out = x + sw * blurW(blurH(softmax_C(xc)))
// Single 24192 B LDS buffer reused IN PLACE across all phases -> 6 blocks/CU
// (was 40320 B / 4 blocks/CU). fp16 staging throughout, float4 global I/O.
//
// In-place safety argument:
//   P3 (vertical blur): task o2 reads/writes ONLY column o2 (all PH rows
//      loaded to registers before any write; columns partition threads 1:1).
//   P4 (horizontal blur): task (h,c) reads/writes ONLY its own (h,c) line
//      (all PW taps loaded to registers first; lines partition tasks 1:1).
//   => no cross-thread overlap in either phase, existing barriers suffice.
//   s is stored fp16 at line slots wt*CC+c, so each s-row is a contiguous
//   336-half run at row*ROWF -> phase 5 reads stay vectorized + aligned.

#define BB    16
#define Himg  384
#define Wimg  384
#define CC    21
#define TH    16
#define TW    16
#define RR    4
#define PH    (TH + 2*RR)          // 24
#define PW    (TW + 2*RR)          // 24
#define ROWF  (PW * CC)            // 504 halves per halo row
#define NPIX  (PH * PW)            // 576
#define OUT_ELEMS (TH * TW * CC)   // 5376
#define CHUNKS_ROW (ROWF / 4)      // 126 float4 per halo row
#define NCHUNK (PH * CHUNKS_ROW)   // 3024
#define NTOT  (BB * Himg * Wimg * CC)  // 49545216 (< 2^31)

__global__ __launch_bounds__(256, 6)
void crf_iter_kernel(const float* __restrict__ xin,
                     const float* __restrict__ unary,
                     float* __restrict__ out,
                     const float* __restrict__ spacings,
                     const float* __restrict__ inv_theta,
                     const float* __restrict__ sw_ptr)
{
    __shared__ __align__(16) unsigned char smem[PH * ROWF * 2];  // 24192 B
    __half* pbuf = (__half*)smem;

    const int tid = threadIdx.x;
    const int b   = blockIdx.z;
    const int h0  = blockIdx.y * TH;
    const int w0  = blockIdx.x * TW;

    const float sp_h = spacings[b * 2 + 0];
    const float sp_w = spacings[b * 2 + 1];
    const float ith  = inv_theta[0];
    const float itw  = inv_theta[1];
    const float sw   = sw_ptr[0];
    float kh[9], kw[9];
#pragma unroll
    for (int i = 0; i < 9; ++i) {
        float dh = sp_h * (float)(i - 4) * ith;
        float dw = sp_w * (float)(i - 4) * itw;
        kh[i] = (i == 4) ? 0.f : __expf(-0.5f * dh * dh);
        kw[i] = (i == 4) ? 0.f : __expf(-0.5f * dw * dw);
    }

    // ---- Phase 1: stage logits halo as fp16 via float4 loads ----
    // Row segment (504 floats) is 16B-aligned for every tile. Addresses are
    // clamped to the tensor; clamped lanes hold garbage but correspond to
    // out-of-image pixels that phase 2 overwrites with 0.
    {
        uint2* pb8 = (uint2*)pbuf;   // 8B store of 4 halves per chunk
        for (int idx = tid; idx < NCHUNK; idx += 256) {
            int r  = idx / CHUNKS_ROW;
            int q  = idx - r * CHUNKS_ROW;
            int hh = h0 - RR + r;
            if (hh >= 0 && hh < Himg) {
                int basef = ((b * Himg + hh) * Wimg + (w0 - RR)) * CC + q * 4;
                int a = basef < 0 ? 0 : (basef > NTOT - 4 ? NTOT - 4 : basef);
                float4 v = *(const float4*)(xin + a);
                __half2 lo = __floats2half2_rn(v.x, v.y);
                __half2 hi = __floats2half2_rn(v.z, v.w);
                uint2 st;
                st.x = *(unsigned int*)&lo;
                st.y = *(unsigned int*)&hi;
                pb8[idx] = st;
            }
            // OOB rows: stale LDS; phase 2 zeroes those pixels.
        }
    }
    __syncthreads();

    // ---- Phase 2: per-pixel softmax over C in place; zero OOB pixels ----
    for (int p = tid; p < NPIX; p += 256) {
        int r   = p / PW;
        int cpx = p - r * PW;
        int hh  = h0 - RR + r;
        int gw  = w0 - RR + cpx;
        __half* px = pbuf + p * CC;
        if (hh >= 0 && hh < Himg && gw >= 0 && gw < Wimg) {
            float v[CC];
            float m = -1e30f;
#pragma unroll
            for (int c = 0; c < CC; ++c) { v[c] = __half2float(px[c]); m = fmaxf(m, v[c]); }
            float s = 0.f;
#pragma unroll
            for (int c = 0; c < CC; ++c) { v[c] = __expf(v[c] - m); s += v[c]; }
            float inv = 1.f / s;
#pragma unroll
            for (int c = 0; c < CC; ++c) px[c] = __float2half_rn(v[c] * inv);
        } else {
            const __half z = __float2half_rn(0.f);
#pragma unroll
            for (int c = 0; c < CC; ++c) px[c] = z;
        }
    }
    __syncthreads();

    // ---- Phase 3: vertical blur, half2 columns, IN PLACE (rows 0..15) ----
    if (tid < ROWF / 2) {
        __half2* pb2 = (__half2*)pbuf;
        const int o2 = tid;
        float2 v[PH];
#pragma unroll
        for (int r = 0; r < PH; ++r) v[r] = __half22float2(pb2[r * (ROWF / 2) + o2]);
#pragma unroll
        for (int t = 0; t < TH; ++t) {
            float ax = 0.f, ay = 0.f;
#pragma unroll
            for (int i = 0; i < 9; ++i) {
                if (i == 4) continue;
                ax = fmaf(kh[i], v[t + i].x, ax);
                ay = fmaf(kh[i], v[t + i].y, ay);
            }
            __half2 o; o.x = __float2half_rn(ax); o.y = __float2half_rn(ay);
            pb2[t * (ROWF / 2) + o2] = o;   // same column, rows 0..15
        }
    }
    __syncthreads();

    // ---- Phase 4: horizontal blur * sw -> fp16 s, IN PLACE per (h,c) line ----
    // |s| <= sw * 0.271^2 * max|p| ~ 0.073 -> fp16 rounding error ~3e-5, negligible.
    for (int o = tid; o < TH * CC; o += 256) {   // 336 tasks: (h, c)
        int h = o / CC;
        int c = o - h * CC;
        __half* line = pbuf + h * ROWF + c;
        float v[PW];
#pragma unroll
        for (int wp = 0; wp < PW; ++wp) v[wp] = __half2float(line[wp * CC]);
#pragma unroll
        for (int wt = 0; wt < TW; ++wt) {
            float acc = 0.f;
#pragma unroll
            for (int j = 0; j < 9; ++j) {
                if (j == 4) continue;
                acc = fmaf(kw[j], v[wt + j], acc);
            }
            line[wt * CC] = __float2half_rn(sw * acc);
        }
    }
    __syncthreads();

    // ---- Phase 5: out = unary + s, float4 RMW (1344 tasks) ----
    // s row h occupies halves [h*ROWF, h*ROWF+336) contiguously
    // (wt*CC + c for wt<16, c<21 enumerates 0..335), 8B-aligned chunks.
    {
        const int gbase = ((b * Himg + h0) * Wimg + w0) * CC;
        for (int j = tid; j < OUT_ELEMS / 4; j += 256) {
            int hrow = j / (TW * CC / 4);            // 84 chunks per h-row
            int qq   = j - hrow * (TW * CC / 4);
            int g = gbase + hrow * (Wimg * CC) + qq * 4;
            float4 u = *(const float4*)(unary + g);
            const __half2* sh = (const __half2*)(pbuf + hrow * ROWF + qq * 4);
            float2 lo = __half22float2(sh[0]);
            float2 hi = __half22float2(sh[1]);
            float4 o;
            o.x = u.x + lo.x; o.y = u.y + lo.y;
            o.z = u.z + hi.x; o.w = u.w + hi.y;
            *(float4*)(out + g) = o;
        }
    }
}

extern "C" void kernel_launch(void* const* d_in, const int* in_sizes, int n_in,
                              void* d_out, int out_size, void* d_ws, size_t ws_size,
                              hipStream_t stream) {
    const float* x         = (const float*)d_in[0];
    const float* spacings  = (const float*)d_in[1];
    const float* sw        = (const float*)d_in[2];
    const float* inv_theta = (const float*)d_in[3];
    float* out = (float*)d_out;
    float* ws  = (float*)d_ws;

    dim3 grid(Wimg / TW, Himg / TH, BB);   // 24 x 24 x 16 = 9216 blocks
    dim3 block(256);

    crf_iter_kernel<<<grid, block, 0, stream>>>(x,   x, out, spacings, inv_theta, sw);
    crf_iter_kernel<<<grid, block, 0, stream>>>(out, x, ws,  spacings, inv_theta, sw);
    crf_iter_kernel<<<grid, block, 0, stream>>>(ws,  x, out, spacings, inv_theta, sw);
    crf_iter_kernel<<<grid, block, 0, stream>>>(out, x, ws,  spacings, inv_theta, sw);
    crf_iter_kernel<<<grid, block, 0, stream>>>(ws,  x, out, spacings, inv_theta, sw);
}

// Round 4
// 918.934 us; speedup vs baseline: 1.2312x; 1.0794x over previous
//
#include <hip/hip_runtime.h>
#include <hip/hip_fp16.h>

// CRF mean-field, NHWC. Per iter: out = x + sw * blurW(blurH(softmax_C(xc)))
//
// R3 (resubmit; previous round was an infra failure, kernel never ran):
// planar channel-pair fp16 LDS + NO staging phase.
//  P2 (fused): per halo pixel, 21 scalar global loads (imm offsets off one
//     base), f32 softmax in registers, packed fp16 store to planar LDS
//     (11 aligned b32; planar row stride = 24 slots so consecutive pixels
//     map to consecutive LDS words -> conflict-free).
//  P3 vblur: per (plane, col): 24 b32 loads, packed v_pk_fma_f16 (inline
//     asm, guaranteed gfx950 VOP3P), in-place rows 0..15.
//  P4 hblur: per (row, plane): 6 b128 loads, pk fma, sw folded into taps,
//     in-place cols 0..15.
//  P5: one output pixel per thread: 11 aligned b32 LDS reads + scalar
//     global unary/out RMW (21 ld + 21 st, imm offsets).
// Gaussian symmetry k[i]==k[8-i]: pair-sum + 4 coeffs (8 pk ops per tap-9
// conv output, 8 coeff VGPRs total).
//
// In-place safety: P3 column-private, P4 row-private (all taps in regs
// before writes); 3 barriers total.
// fp16 API surface limited to what R0/R1 proved on ROCm 7.2:
// __half2float / __floats2half2_rn / __half22float2 / pointer __half2.
// Packed math via inline asm only (v_pk_{add,mul,fma}_f16).

#define BB    16
#define Himg  384
#define Wimg  384
#define CC    21
#define NP    11                   // channel pairs (last = c20 + zero pad)
#define TH    16
#define TW    16
#define RR    4
#define PH    (TH + 2*RR)          // 24
#define PW    (TW + 2*RR)          // 24
#define NPIX  (PH * PW)            // 576
#define PLANE_B 2384               // plane stride bytes (2304 + 80 pad; /4 %32 = 20)
#define ROW_B   (PW * 4)           // 96 B per plane row (24 slots)
#define NTASK (PW * NP)            // 264 (col, plane) tasks

static __device__ __forceinline__ unsigned int pk_add(unsigned int a, unsigned int b) {
    unsigned int d; asm("v_pk_add_f16 %0, %1, %2" : "=v"(d) : "v"(a), "v"(b)); return d;
}
static __device__ __forceinline__ unsigned int pk_mul(unsigned int a, unsigned int b) {
    unsigned int d; asm("v_pk_mul_f16 %0, %1, %2" : "=v"(d) : "v"(a), "v"(b)); return d;
}
static __device__ __forceinline__ unsigned int pk_fma(unsigned int a, unsigned int b, unsigned int c) {
    unsigned int d; asm("v_pk_fma_f16 %0, %1, %2, %3" : "=v"(d) : "v"(a), "v"(b), "v"(c)); return d;
}

__global__ __launch_bounds__(256, 6)
void crf_iter_kernel(const float* __restrict__ xin,
                     const float* __restrict__ unary,
                     float* __restrict__ out,
                     const float* __restrict__ spacings,
                     const float* __restrict__ inv_theta,
                     const float* __restrict__ sw_ptr)
{
    __shared__ __align__(16) unsigned char smem[NP * PLANE_B];  // 26224 B

    const int tid = threadIdx.x;
    const int b   = blockIdx.z;
    const int h0  = blockIdx.y * TH;
    const int w0  = blockIdx.x * TW;

    const float sp_h = spacings[b * 2 + 0];
    const float sp_w = spacings[b * 2 + 1];
    const float ith  = inv_theta[0];
    const float itw  = inv_theta[1];
    const float sw   = sw_ptr[0];
    // symmetric taps: k[i] == k[8-i]; center (i==4) excluded. Keep 4 each.
    unsigned int khp[4], kwp[4];
#pragma unroll
    for (int i = 0; i < 4; ++i) {
        float dh = sp_h * (float)(i - 4) * ith;
        float dw = sp_w * (float)(i - 4) * itw;
        float kh = __expf(-0.5f * dh * dh);
        float kw = sw * __expf(-0.5f * dw * dw);   // fold sw into horizontal
        __half2 a = __floats2half2_rn(kh, kh);
        __half2 c = __floats2half2_rn(kw, kw);
        khp[i] = *(unsigned int*)&a;
        kwp[i] = *(unsigned int*)&c;
    }

    // ---- Phase 2 (fused stage+softmax): global -> regs -> planar LDS ----
    for (int p = tid; p < NPIX; p += 256) {
        const int r  = p / PW;
        const int px = p - r * PW;
        const int hh = h0 - RR + r;
        const int gw = w0 - RR + px;
        // planar slot: addr/4 = p + plane*596 -> consecutive lanes,
        // consecutive banks: conflict-free.
        unsigned char* lbase = smem + p * 4;
        if (hh >= 0 && hh < Himg && gw >= 0 && gw < Wimg) {
            const float* gp = xin + ((b * Himg + hh) * Wimg + gw) * CC;
            float v[CC];
#pragma unroll
            for (int c = 0; c < CC; ++c) v[c] = gp[c];   // 21 dword, imm offs
            float m = v[0];
#pragma unroll
            for (int c = 1; c < CC; ++c) m = fmaxf(m, v[c]);
            float s = 0.f;
#pragma unroll
            for (int c = 0; c < CC; ++c) { v[c] = __expf(v[c] - m); s += v[c]; }
            const float inv = 1.0f / s;
#pragma unroll
            for (int cp = 0; cp < 10; ++cp) {
                __half2 hx = __floats2half2_rn(v[2*cp] * inv, v[2*cp+1] * inv);
                *(__half2*)(lbase + cp * PLANE_B) = hx;
            }
            __half2 hl = __floats2half2_rn(v[20] * inv, 0.f);  // pad slot = 0
            *(__half2*)(lbase + 10 * PLANE_B) = hl;
        } else {
            const __half2 z = __floats2half2_rn(0.f, 0.f);
#pragma unroll
            for (int cp = 0; cp < NP; ++cp)
                *(__half2*)(lbase + cp * PLANE_B) = z;
        }
    }
    __syncthreads();

    // ---- Phase 3: vertical blur, packed fp16, in place (rows 0..15) ----
    for (int t = tid; t < NTASK; t += 256) {
        const int cp  = t / PW;
        const int col = t - cp * PW;
        unsigned char* base = smem + cp * PLANE_B + col * 4;
        unsigned int v[PH];
#pragma unroll
        for (int r = 0; r < PH; ++r) v[r] = *(const unsigned int*)(base + r * ROW_B);
#pragma unroll
        for (int tt = 0; tt < TH; ++tt) {
            // symmetric pairs around center tt+4
            unsigned int s0 = pk_add(v[tt],     v[tt + 8]);
            unsigned int s1 = pk_add(v[tt + 1], v[tt + 7]);
            unsigned int s2 = pk_add(v[tt + 2], v[tt + 6]);
            unsigned int s3 = pk_add(v[tt + 3], v[tt + 5]);
            unsigned int acc = pk_mul(khp[0], s0);
            acc = pk_fma(khp[1], s1, acc);
            acc = pk_fma(khp[2], s2, acc);
            acc = pk_fma(khp[3], s3, acc);
            *(unsigned int*)(base + tt * ROW_B) = acc;
        }
    }
    __syncthreads();

    // ---- Phase 4: horizontal blur * sw, b128 rows, in place (cols 0..15) ----
    if (tid < TH * NP) {                   // 176 tasks
        const int h  = tid / NP;
        const int cp = tid - h * NP;
        unsigned char* base = smem + cp * PLANE_B + h * ROW_B;
        unsigned int v[PW];
#pragma unroll
        for (int k = 0; k < 6; ++k) {
            const uint4 q = *(const uint4*)(base + k * 16);
            v[4*k+0] = q.x; v[4*k+1] = q.y; v[4*k+2] = q.z; v[4*k+3] = q.w;
        }
        unsigned int o[TW];
#pragma unroll
        for (int wt = 0; wt < TW; ++wt) {
            unsigned int s0 = pk_add(v[wt],     v[wt + 8]);
            unsigned int s1 = pk_add(v[wt + 1], v[wt + 7]);
            unsigned int s2 = pk_add(v[wt + 2], v[wt + 6]);
            unsigned int s3 = pk_add(v[wt + 3], v[wt + 5]);
            unsigned int acc = pk_mul(kwp[0], s0);
            acc = pk_fma(kwp[1], s1, acc);
            acc = pk_fma(kwp[2], s2, acc);
            acc = pk_fma(kwp[3], s3, acc);
            o[wt] = acc;
        }
#pragma unroll
        for (int k = 0; k < 4; ++k) {
            uint4 wq;
            wq.x = o[4*k+0]; wq.y = o[4*k+1]; wq.z = o[4*k+2]; wq.w = o[4*k+3];
            *(uint4*)(base + k * 16) = wq;
        }
    }
    __syncthreads();

    // ---- Phase 5: one output pixel per thread: out = unary + s ----
    {
        const int r  = tid >> 4;           // 0..15 (tile row)
        const int px = tid & 15;           // 0..15 (tile col)
        // s lives at planar rows 0..15, cols 0..15
        unsigned char* lbase = smem + (r * PW + px) * 4;
        float sv[CC + 1];
#pragma unroll
        for (int cp = 0; cp < NP; ++cp) {
            float2 f = __half22float2(*(const __half2*)(lbase + cp * PLANE_B));
            sv[2*cp] = f.x; sv[2*cp+1] = f.y;
        }
        const int g = ((b * Himg + h0 + r) * Wimg + (w0 + px)) * CC;
        const float* up = unary + g;
        float* op = out + g;
#pragma unroll
        for (int c = 0; c < CC; ++c) op[c] = up[c] + sv[c];
    }
}

extern "C" void kernel_launch(void* const* d_in, const int* in_sizes, int n_in,
                              void* d_out, int out_size, void* d_ws, size_t ws_size,
                              hipStream_t stream) {
    const float* x         = (const float*)d_in[0];
    const float* spacings  = (const float*)d_in[1];
    const float* sw        = (const float*)d_in[2];
    const float* inv_theta = (const float*)d_in[3];
    float* out = (float*)d_out;
    float* ws  = (float*)d_ws;

    dim3 grid(Wimg / TW, Himg / TH, BB);   // 24 x 24 x 16 = 9216 blocks
    dim3 block(256);

    crf_iter_kernel<<<grid, block, 0, stream>>>(x,   x, out, spacings, inv_theta, sw);
    crf_iter_kernel<<<grid, block, 0, stream>>>(out, x, ws,  spacings, inv_theta, sw);
    crf_iter_kernel<<<grid, block, 0, stream>>>(ws,  x, out, spacings, inv_theta, sw);
    crf_iter_kernel<<<grid, block, 0, stream>>>(out, x, ws,  spacings, inv_theta, sw);
    crf_iter_kernel<<<grid, block, 0, stream>>>(ws,  x, out, spacings, inv_theta, sw);
}